// Round 1
// baseline (151.383 us; speedup 1.0000x reference)
//
#include <hip/hip_runtime.h>
#include <math.h>

// ---------- constants (normalization folded per the reference) ----------
#define SQ15f      3.8729833462074170f   // sqrt(15)
#define SQ5f       2.2360679774997896f   // sqrt(5)
#define C2_XZ      1.7320508075688772f   // sqrt(15)/sqrt(5) = sqrt(3)
#define C2_ZX      0.8660254037844386f   // (sqrt(15)/2)/sqrt(5) = sqrt(3)/2
#define C3_A       0.4082482904638631f   // (sqrt(42)/6)/sqrt(7) = 1/sqrt(6)
#define C3_B       0.6123724356957945f   // (sqrt(168)/8)/sqrt(7) = sqrt(24)/8
#define EMB_SCALE  2.8234622000789103f   // sqrt(10)/1.12

__global__ void hdr_feat_kernel(const float* __restrict__ feat,
                                float* __restrict__ out, int n2) {
    int i = blockIdx.x * blockDim.x + threadIdx.x;
    if (i == 0) { out[0] = 10.0f; out[1] = 1000.0f; }  // Nt, Ny
    if (i < n2) {
        float2 v = ((const float2*)feat)[i];
        ((float2*)(out + 2))[i] = v;
    }
}

__global__ void edge_kernel(const float* __restrict__ pos,
                            const float* __restrict__ qpos,
                            const int*   __restrict__ esrc,
                            const int*   __restrict__ edst,
                            float* __restrict__ out_src,
                            float* __restrict__ out_dst,
                            float* __restrict__ out_emb,
                            float* __restrict__ out_sh,
                            float* __restrict__ out_len,
                            int E) {
    int e = blockIdx.x * blockDim.x + threadIdx.x;
    if (e >= E) return;

    int s = esrc[e];
    int d = edst[e];

    // gathers: query table 120 KB, pos table 60 KB -> cache-resident
    float vx = qpos[3 * s + 0] - pos[3 * d + 0];
    float vy = qpos[3 * s + 1] - pos[3 * d + 1];
    float vz = qpos[3 * s + 2] - pos[3 * d + 2];

    float ss  = vx * vx + vy * vy + vz * vz;
    float len = sqrtf(ss + 1e-8f);           // edge_length (CUTOFF = 1)

    // ---- spherical harmonics (normalize=True) ----
    float n   = sqrtf(ss);
    float inv = 1.0f / fmaxf(n, 1e-12f);
    float x = vx * inv, y = vy * inv, z = vz * inv;

    float x2 = x * x, y2 = y * y, z2 = z * z;
    float x2z2 = x2 + z2;

    float s20 = SQ15f * x * z;
    float s24 = 0.5f * SQ15f * (z2 - x2);
    float q   = 4.0f * y2 - x2z2;

    float sh[16];
    sh[0] = 1.0f;
    sh[1] = x;  sh[2] = y;  sh[3] = z;
    sh[4] = C2_XZ * x * z;
    sh[5] = C2_XZ * x * y;
    sh[6] = y2 - 0.5f * x2z2;
    sh[7] = C2_XZ * y * z;
    sh[8] = C2_ZX * (z2 - x2);
    sh[9]  = C3_A * (s20 * z + s24 * x);
    sh[10] = s20 * y;                        // SQ7*s20*y / SQ7
    sh[11] = C3_B * q * x;
    sh[12] = 0.5f * y * (2.0f * y2 - 3.0f * x2z2);
    sh[13] = C3_B * z * q;
    sh[14] = s24 * y;
    sh[15] = C3_A * (s24 * z - s20 * x);

    // ---- gaussian basis * soft cutoff ----
    // t = ((1-len) - 0.8)/0.2 * 1.1
    float t = (0.2f - len) * 5.5f;
    float cut;
    if (t <= 0.0f)      cut = 1.0f;
    else if (t >= 1.0f) cut = 0.0f;
    else {
        float t2 = t * t;
        float t4 = t2 * t2;
        cut = 1.0f - (5.0f * t4 - 4.0f * t4 * t);
    }
    float cs = cut * EMB_SCALE;

    float emb[10];
#pragma unroll
    for (int i = 0; i < 10; ++i) {
        float m  = (9.0f + 8.0f * (float)i) * (1.0f / 81.0f);  // linspace(1/9,1,10)
        float dd = (len - m) * 9.0f;                            // /dx, dx=1/9
        emb[i] = expf(-dd * dd) * cs;
    }

    // ---- stores (regions are 8B-aligned; rows even-length -> float2 ok) ----
    out_src[e] = (float)s;
    out_dst[e] = (float)d;

    float2* ep = (float2*)(out_emb + (size_t)10 * e);
#pragma unroll
    for (int i = 0; i < 5; ++i) ep[i] = make_float2(emb[2 * i], emb[2 * i + 1]);

    float2* sp = (float2*)(out_sh + (size_t)16 * e);
#pragma unroll
    for (int i = 0; i < 8; ++i) sp[i] = make_float2(sh[2 * i], sh[2 * i + 1]);

    out_len[e] = len;
}

extern "C" void kernel_launch(void* const* d_in, const int* in_sizes, int n_in,
                              void* d_out, int out_size, void* d_ws, size_t ws_size,
                              hipStream_t stream) {
    const float* pos  = (const float*)d_in[0];
    const float* qpos = (const float*)d_in[1];
    const float* feat = (const float*)d_in[2];
    const int*   esrc = (const int*)d_in[3];
    const int*   edst = (const int*)d_in[4];
    float* out = (float*)d_out;

    const int Ftot = in_sizes[2];   // 320000
    const int E    = in_sizes[3];   // 3000000

    const size_t OFF_FEAT = 2;
    const size_t OFF_SRC  = OFF_FEAT + (size_t)Ftot;
    const size_t OFF_DST  = OFF_SRC + (size_t)E;
    const size_t OFF_EMB  = OFF_DST + (size_t)E;
    const size_t OFF_SH   = OFF_EMB + (size_t)10 * E;
    const size_t OFF_LEN  = OFF_SH  + (size_t)16 * E;

    int n2 = Ftot / 2;
    hdr_feat_kernel<<<(n2 + 255) / 256, 256, 0, stream>>>(feat, out, n2);

    edge_kernel<<<(E + 255) / 256, 256, 0, stream>>>(
        pos, qpos, esrc, edst,
        out + OFF_SRC, out + OFF_DST, out + OFF_EMB, out + OFF_SH, out + OFF_LEN, E);
}

// Round 2
// 125.928 us; speedup vs baseline: 1.2021x; 1.2021x over previous
//
#include <hip/hip_runtime.h>
#include <math.h>

// ---------- constants (normalization folded per the reference) ----------
#define SQ15f      3.8729833462074170f   // sqrt(15)
#define C2_XZ      1.7320508075688772f   // sqrt(15)/sqrt(5) = sqrt(3)
#define C2_ZX      0.8660254037844386f   // (sqrt(15)/2)/sqrt(5) = sqrt(3)/2
#define C3_A       0.4082482904638631f   // (sqrt(42)/6)/sqrt(7) = 1/sqrt(6)
#define C3_B       0.6123724356957945f   // (sqrt(168)/8)/sqrt(7) = sqrt(24)/8
#define EMB_SCALE  2.8234622000789103f   // sqrt(10)/1.12

#define EPAD 11   // emb LDS row stride (odd -> conflict-light)
#define SPAD 17   // sh  LDS row stride

__global__ void hdr_feat_kernel(const float* __restrict__ feat,
                                float* __restrict__ out, int n2) {
    int i = blockIdx.x * blockDim.x + threadIdx.x;
    if (i == 0) { out[0] = 10.0f; out[1] = 1000.0f; }  // Nt, Ny
    if (i < n2) {
        float2 v = ((const float2*)feat)[i];
        ((float2*)(out + 2))[i] = v;
    }
}

__global__ __launch_bounds__(256)
void edge_kernel(const float* __restrict__ pos,
                 const float* __restrict__ qpos,
                 const int*   __restrict__ esrc,
                 const int*   __restrict__ edst,
                 float* __restrict__ out_src,
                 float* __restrict__ out_dst,
                 float* __restrict__ out_emb,
                 float* __restrict__ out_sh,
                 float* __restrict__ out_len,
                 int E) {
    __shared__ float semb[256 * EPAD];
    __shared__ float ssh [256 * SPAD];

    const int tid  = threadIdx.x;
    const int base = blockIdx.x * 256;
    const int nb   = min(256, E - base);
    const int e    = base + tid;

    if (tid < nb) {
        int s = esrc[e];
        int d = edst[e];

        // gathers: query table 120 KB, pos table 60 KB -> cache-resident
        float vx = qpos[3 * s + 0] - pos[3 * d + 0];
        float vy = qpos[3 * s + 1] - pos[3 * d + 1];
        float vz = qpos[3 * s + 2] - pos[3 * d + 2];

        float ss  = vx * vx + vy * vy + vz * vz;
        float len = sqrtf(ss + 1e-8f);           // edge_length (CUTOFF = 1)

        // ---- spherical harmonics (normalize=True, 'norm' normalization) ----
        float n   = sqrtf(ss);
        float inv = 1.0f / fmaxf(n, 1e-12f);
        float x = vx * inv, y = vy * inv, z = vz * inv;

        float x2 = x * x, y2 = y * y, z2 = z * z;
        float x2z2 = x2 + z2;

        float s20 = SQ15f * x * z;
        float s24 = 0.5f * SQ15f * (z2 - x2);
        float q   = 4.0f * y2 - x2z2;

        float* sh = &ssh[tid * SPAD];
        sh[0] = 1.0f;
        sh[1] = x;  sh[2] = y;  sh[3] = z;
        sh[4] = C2_XZ * x * z;
        sh[5] = C2_XZ * x * y;
        sh[6] = y2 - 0.5f * x2z2;
        sh[7] = C2_XZ * y * z;
        sh[8] = C2_ZX * (z2 - x2);
        sh[9]  = C3_A * (s20 * z + s24 * x);
        sh[10] = s20 * y;
        sh[11] = C3_B * q * x;
        sh[12] = 0.5f * y * (2.0f * y2 - 3.0f * x2z2);
        sh[13] = C3_B * z * q;
        sh[14] = s24 * y;
        sh[15] = C3_A * (s24 * z - s20 * x);

        // ---- gaussian basis * quintic soft cutoff ----
        float t = (0.2f - len) * 5.5f;
        float cut;
        if (t <= 0.0f)      cut = 1.0f;
        else if (t >= 1.0f) cut = 0.0f;
        else {
            float t2 = t * t;
            float t4 = t2 * t2;
            cut = 1.0f - (5.0f * t4 - 4.0f * t4 * t);
        }
        float cs = cut * EMB_SCALE;

        float* em = &semb[tid * EPAD];
#pragma unroll
        for (int i = 0; i < 10; ++i) {
            float m  = (9.0f + 8.0f * (float)i) * (1.0f / 81.0f);  // linspace(1/9,1,10)
            float dd = (len - m) * 9.0f;
            em[i] = expf(-dd * dd) * cs;
        }

        // already coalesced (4 B/lane):
        out_src[e] = (float)s;
        out_dst[e] = (float)d;
        out_len[e] = len;
    }
    __syncthreads();

    // ---- cooperative coalesced block writes (regions are 8B-aligned) ----
    float2* ebase = (float2*)(out_emb + (size_t)10 * base);
    float2* sbase = (float2*)(out_sh  + (size_t)16 * base);

    if (nb == 256) {
#pragma unroll
        for (int i = 0; i < 5; ++i) {           // 1280 float2 total
            int k  = i * 256 + tid;
            int el = k / 5, c = (k - el * 5) * 2;
            ebase[k] = make_float2(semb[el * EPAD + c], semb[el * EPAD + c + 1]);
        }
#pragma unroll
        for (int i = 0; i < 8; ++i) {           // 2048 float2 total
            int k  = i * 256 + tid;
            int el = k >> 3, c = (k & 7) * 2;
            sbase[k] = make_float2(ssh[el * SPAD + c], ssh[el * SPAD + c + 1]);
        }
    } else {
        for (int k = tid; k < nb * 5; k += 256) {
            int el = k / 5, c = (k - el * 5) * 2;
            ebase[k] = make_float2(semb[el * EPAD + c], semb[el * EPAD + c + 1]);
        }
        for (int k = tid; k < nb * 8; k += 256) {
            int el = k >> 3, c = (k & 7) * 2;
            sbase[k] = make_float2(ssh[el * SPAD + c], ssh[el * SPAD + c + 1]);
        }
    }
}

extern "C" void kernel_launch(void* const* d_in, const int* in_sizes, int n_in,
                              void* d_out, int out_size, void* d_ws, size_t ws_size,
                              hipStream_t stream) {
    const float* pos  = (const float*)d_in[0];
    const float* qpos = (const float*)d_in[1];
    const float* feat = (const float*)d_in[2];
    const int*   esrc = (const int*)d_in[3];
    const int*   edst = (const int*)d_in[4];
    float* out = (float*)d_out;

    const int Ftot = in_sizes[2];   // 320000
    const int E    = in_sizes[3];   // 3000000

    const size_t OFF_FEAT = 2;
    const size_t OFF_SRC  = OFF_FEAT + (size_t)Ftot;
    const size_t OFF_DST  = OFF_SRC + (size_t)E;
    const size_t OFF_EMB  = OFF_DST + (size_t)E;
    const size_t OFF_SH   = OFF_EMB + (size_t)10 * E;
    const size_t OFF_LEN  = OFF_SH  + (size_t)16 * E;

    int n2 = Ftot / 2;
    hdr_feat_kernel<<<(n2 + 255) / 256, 256, 0, stream>>>(feat, out, n2);

    int nblk = (E + 255) / 256;
    edge_kernel<<<nblk, 256, 0, stream>>>(
        pos, qpos, esrc, edst,
        out + OFF_SRC, out + OFF_DST, out + OFF_EMB, out + OFF_SH, out + OFF_LEN, E);
}

// Round 4
// 103.110 us; speedup vs baseline: 1.4682x; 1.2213x over previous
//
#include <hip/hip_runtime.h>
#include <math.h>

// ---------- constants (normalization folded per the reference) ----------
#define SQ15f      3.8729833462074170f   // sqrt(15)
#define C2_XZ      1.7320508075688772f   // sqrt(15)/sqrt(5) = sqrt(3)
#define C2_ZX      0.8660254037844386f   // (sqrt(15)/2)/sqrt(5) = sqrt(3)/2
#define C3_A       0.4082482904638631f   // (sqrt(42)/6)/sqrt(7) = 1/sqrt(6)
#define C3_B       0.6123724356957945f   // (sqrt(168)/8)/sqrt(7) = sqrt(24)/8
#define EMB_SCALE  2.8234622000789103f   // sqrt(10)/1.12

#define EPAD 11   // emb LDS row stride
#define SPAD 17   // sh  LDS row stride

typedef float v2f __attribute__((ext_vector_type(2)));   // clang vector: OK for nontemporal builtins

__global__ void hdr_feat_kernel(const float* __restrict__ feat,
                                float* __restrict__ out, int n2) {
    int i = blockIdx.x * blockDim.x + threadIdx.x;
    if (i == 0) { out[0] = 10.0f; out[1] = 1000.0f; }  // Nt, Ny
    if (i < n2) {
        v2f v = __builtin_nontemporal_load(((const v2f*)feat) + i);
        __builtin_nontemporal_store(v, ((v2f*)(out + 2)) + i);
    }
}

__global__ __launch_bounds__(256)
void edge_kernel(const float* __restrict__ pos,
                 const float* __restrict__ qpos,
                 const int*   __restrict__ esrc,
                 const int*   __restrict__ edst,
                 float* __restrict__ out_src,
                 float* __restrict__ out_dst,
                 float* __restrict__ out_emb,
                 float* __restrict__ out_sh,
                 float* __restrict__ out_len,
                 int E) {
    __shared__ float semb[256 * EPAD];
    __shared__ float ssh [256 * SPAD];

    const int tid  = threadIdx.x;
    const int base = blockIdx.x * 256;
    const int nb   = min(256, E - base);
    const int e    = base + tid;

    if (tid < nb) {
        int s = __builtin_nontemporal_load(esrc + e);
        int d = __builtin_nontemporal_load(edst + e);

        // gathers: query table 120 KB, pos table 60 KB -> L2-resident (keep cached)
        float vx = qpos[3 * s + 0] - pos[3 * d + 0];
        float vy = qpos[3 * s + 1] - pos[3 * d + 1];
        float vz = qpos[3 * s + 2] - pos[3 * d + 2];

        float ss  = vx * vx + vy * vy + vz * vz;
        float len = sqrtf(ss + 1e-8f);           // edge_length (CUTOFF = 1)

        // ---- spherical harmonics (normalize=True, 'norm' normalization) ----
        float n   = sqrtf(ss);
        float inv = 1.0f / fmaxf(n, 1e-12f);
        float x = vx * inv, y = vy * inv, z = vz * inv;

        float x2 = x * x, y2 = y * y, z2 = z * z;
        float x2z2 = x2 + z2;

        float s20 = SQ15f * x * z;
        float s24 = 0.5f * SQ15f * (z2 - x2);
        float q   = 4.0f * y2 - x2z2;

        float* sh = &ssh[tid * SPAD];
        sh[0] = 1.0f;
        sh[1] = x;  sh[2] = y;  sh[3] = z;
        sh[4] = C2_XZ * x * z;
        sh[5] = C2_XZ * x * y;
        sh[6] = y2 - 0.5f * x2z2;
        sh[7] = C2_XZ * y * z;
        sh[8] = C2_ZX * (z2 - x2);
        sh[9]  = C3_A * (s20 * z + s24 * x);
        sh[10] = s20 * y;
        sh[11] = C3_B * q * x;
        sh[12] = 0.5f * y * (2.0f * y2 - 3.0f * x2z2);
        sh[13] = C3_B * z * q;
        sh[14] = s24 * y;
        sh[15] = C3_A * (s24 * z - s20 * x);

        // ---- gaussian basis * quintic soft cutoff ----
        float t = (0.2f - len) * 5.5f;
        float cut;
        if (t <= 0.0f)      cut = 1.0f;
        else if (t >= 1.0f) cut = 0.0f;
        else {
            float t2 = t * t;
            float t4 = t2 * t2;
            cut = 1.0f - (5.0f * t4 - 4.0f * t4 * t);
        }
        float cs = cut * EMB_SCALE;

        float* em = &semb[tid * EPAD];
#pragma unroll
        for (int i = 0; i < 10; ++i) {
            float m  = (9.0f + 8.0f * (float)i) * (1.0f / 81.0f);  // linspace(1/9,1,10)
            float dd = (len - m) * 9.0f;
            em[i] = __expf(-dd * dd) * cs;
        }

        // coalesced 4 B/lane streams:
        __builtin_nontemporal_store((float)s, out_src + e);
        __builtin_nontemporal_store((float)d, out_dst + e);
        __builtin_nontemporal_store(len,      out_len + e);
    }
    __syncthreads();

    // ---- cooperative coalesced block writes (regions are 8B-aligned) ----
    v2f* ebase = (v2f*)(out_emb + (size_t)10 * base);
    v2f* sbase = (v2f*)(out_sh  + (size_t)16 * base);

    if (nb == 256) {
#pragma unroll
        for (int i = 0; i < 5; ++i) {           // 1280 v2f total
            int k  = i * 256 + tid;
            int el = k / 5, c = (k - el * 5) * 2;
            v2f v = { semb[el * EPAD + c], semb[el * EPAD + c + 1] };
            __builtin_nontemporal_store(v, ebase + k);
        }
#pragma unroll
        for (int i = 0; i < 8; ++i) {           // 2048 v2f total
            int k  = i * 256 + tid;
            int el = k >> 3, c = (k & 7) * 2;
            v2f v = { ssh[el * SPAD + c], ssh[el * SPAD + c + 1] };
            __builtin_nontemporal_store(v, sbase + k);
        }
    } else {
        for (int k = tid; k < nb * 5; k += 256) {
            int el = k / 5, c = (k - el * 5) * 2;
            v2f v = { semb[el * EPAD + c], semb[el * EPAD + c + 1] };
            __builtin_nontemporal_store(v, ebase + k);
        }
        for (int k = tid; k < nb * 8; k += 256) {
            int el = k >> 3, c = (k & 7) * 2;
            v2f v = { ssh[el * SPAD + c], ssh[el * SPAD + c + 1] };
            __builtin_nontemporal_store(v, sbase + k);
        }
    }
}

extern "C" void kernel_launch(void* const* d_in, const int* in_sizes, int n_in,
                              void* d_out, int out_size, void* d_ws, size_t ws_size,
                              hipStream_t stream) {
    const float* pos  = (const float*)d_in[0];
    const float* qpos = (const float*)d_in[1];
    const float* feat = (const float*)d_in[2];
    const int*   esrc = (const int*)d_in[3];
    const int*   edst = (const int*)d_in[4];
    float* out = (float*)d_out;

    const int Ftot = in_sizes[2];   // 320000
    const int E    = in_sizes[3];   // 3000000

    const size_t OFF_FEAT = 2;
    const size_t OFF_SRC  = OFF_FEAT + (size_t)Ftot;
    const size_t OFF_DST  = OFF_SRC + (size_t)E;
    const size_t OFF_EMB  = OFF_DST + (size_t)E;
    const size_t OFF_SH   = OFF_EMB + (size_t)10 * E;
    const size_t OFF_LEN  = OFF_SH  + (size_t)16 * E;

    int n2 = Ftot / 2;
    hdr_feat_kernel<<<(n2 + 255) / 256, 256, 0, stream>>>(feat, out, n2);

    int nblk = (E + 255) / 256;
    edge_kernel<<<nblk, 256, 0, stream>>>(
        pos, qpos, esrc, edst,
        out + OFF_SRC, out + OFF_DST, out + OFF_EMB, out + OFF_SH, out + OFF_LEN, E);
}

// Round 5
// 92.515 us; speedup vs baseline: 1.6363x; 1.1145x over previous
//
#include <hip/hip_runtime.h>
#include <math.h>

// ---------- constants (normalization folded per the reference) ----------
#define SQ15f      3.8729833462074170f   // sqrt(15)
#define C2_XZ      1.7320508075688772f   // sqrt(3)
#define C2_ZX      0.8660254037844386f   // sqrt(3)/2
#define C3_A       0.4082482904638631f   // 1/sqrt(6)
#define C3_B       0.6123724356957945f   // sqrt(24)/8
#define EMB_SCALE  2.8234622000789103f   // sqrt(10)/1.12

typedef float v2f __attribute__((ext_vector_type(2)));
typedef float v4f __attribute__((ext_vector_type(4)));

// sh LDS layout: logical in-block float g (0..4095) lives at ssh[g + (g>>4)]
// == row-major [256][16] padded to stride 17 (write stride 17: conflict-free).
// emb LDS layout: plain linear [2560] (write stride 10: 4-way, cheap; reads linear).

__global__ __launch_bounds__(256)
void fused_kernel(const float* __restrict__ pos,
                  const float* __restrict__ qpos,
                  const float* __restrict__ feat,
                  const int*   __restrict__ esrc,
                  const int*   __restrict__ edst,
                  float* __restrict__ out,
                  int E, int nblk_edge, int n2feat,
                  unsigned long long OFF_SRC, unsigned long long OFF_DST,
                  unsigned long long OFF_EMB, unsigned long long OFF_SH,
                  unsigned long long OFF_LEN) {
    const int tid = threadIdx.x;
    const int blk = blockIdx.x;

    if (blk >= nblk_edge) {                 // ---- feature passthrough blocks ----
        int i = (blk - nblk_edge) * 256 + tid;
        if (i == 0) { out[0] = 10.0f; out[1] = 1000.0f; }   // Nt, Ny
        if (i < n2feat) {
            v2f v = __builtin_nontemporal_load(((const v2f*)feat) + i);
            __builtin_nontemporal_store(v, ((v2f*)(out + 2)) + i);
        }
        return;
    }

    __shared__ float semb[2560];
    __shared__ float ssh [4352];

    const int base = blk * 256;
    const int nb   = min(256, E - base);
    const int e    = base + tid;

    if (tid < nb) {
        int s = __builtin_nontemporal_load(esrc + e);
        int d = __builtin_nontemporal_load(edst + e);

        float vx = qpos[3 * s + 0] - pos[3 * d + 0];
        float vy = qpos[3 * s + 1] - pos[3 * d + 1];
        float vz = qpos[3 * s + 2] - pos[3 * d + 2];

        float ss  = vx * vx + vy * vy + vz * vz;
        float len = sqrtf(ss + 1e-8f);

        float n   = sqrtf(ss);
        float inv = 1.0f / fmaxf(n, 1e-12f);
        float x = vx * inv, y = vy * inv, z = vz * inv;

        float x2 = x * x, y2 = y * y, z2 = z * z;
        float x2z2 = x2 + z2;

        float s20 = SQ15f * x * z;
        float s24 = 0.5f * SQ15f * (z2 - x2);
        float q   = 4.0f * y2 - x2z2;

        float* sh = &ssh[tid * 17];
        sh[0] = 1.0f;
        sh[1] = x;  sh[2] = y;  sh[3] = z;
        sh[4] = C2_XZ * x * z;
        sh[5] = C2_XZ * x * y;
        sh[6] = y2 - 0.5f * x2z2;
        sh[7] = C2_XZ * y * z;
        sh[8] = C2_ZX * (z2 - x2);
        sh[9]  = C3_A * (s20 * z + s24 * x);
        sh[10] = s20 * y;
        sh[11] = C3_B * q * x;
        sh[12] = 0.5f * y * (2.0f * y2 - 3.0f * x2z2);
        sh[13] = C3_B * z * q;
        sh[14] = s24 * y;
        sh[15] = C3_A * (s24 * z - s20 * x);

        float t = (0.2f - len) * 5.5f;
        float cut;
        if (t <= 0.0f)      cut = 1.0f;
        else if (t >= 1.0f) cut = 0.0f;
        else {
            float t2 = t * t;
            float t4 = t2 * t2;
            cut = 1.0f - (5.0f * t4 - 4.0f * t4 * t);
        }
        float cs = cut * EMB_SCALE;

        float* em = &semb[tid * 10];
#pragma unroll
        for (int i = 0; i < 10; ++i) {
            float m  = (9.0f + 8.0f * (float)i) * (1.0f / 81.0f);
            float dd = (len - m) * 9.0f;
            em[i] = __expf(-dd * dd) * cs;
        }

        __builtin_nontemporal_store((float)s, out + OFF_SRC + e);
        __builtin_nontemporal_store((float)d, out + OFF_DST + e);
        __builtin_nontemporal_store(len,      out + OFF_LEN + e);
    }
    __syncthreads();

    float* egb = out + OFF_EMB + (size_t)10 * base;   // block emb span (base ≡2 mod 4)
    float* sgb = out + OFF_SH  + (size_t)16 * base;   // block sh  span (base ≡2 mod 4)

    if (nb == 256) {
        // ---- emb: head v2f + 639 aligned v4f + tail v2f ----
#pragma unroll
        for (int i = 0; i < 3; ++i) {
            int idx = i * 256 + tid;
            if (idx < 639) {
                int p = 2 + 4 * idx;
                v4f v = { semb[p], semb[p + 1], semb[p + 2], semb[p + 3] };
                __builtin_nontemporal_store(v, (v4f*)(egb + p));
            }
        }
        if (tid == 0) { v2f h = { semb[0], semb[1] };        __builtin_nontemporal_store(h, (v2f*)egb); }
        if (tid == 1) { v2f tl = { semb[2558], semb[2559] }; __builtin_nontemporal_store(tl, (v2f*)(egb + 2558)); }

        // ---- sh: head v2f + 1023 aligned v4f + tail v2f ----
#pragma unroll
        for (int i = 0; i < 4; ++i) {
            int idx = i * 256 + tid;
            if (idx < 1023) {
                int g0 = 2 + 4 * idx;
                v4f v = { ssh[g0 + (g0 >> 4)],
                          ssh[(g0 + 1) + ((g0 + 1) >> 4)],
                          ssh[(g0 + 2) + ((g0 + 2) >> 4)],
                          ssh[(g0 + 3) + ((g0 + 3) >> 4)] };
                __builtin_nontemporal_store(v, (v4f*)(sgb + g0));
            }
        }
        if (tid == 2) { v2f h = { ssh[0], ssh[1] };           __builtin_nontemporal_store(h, (v2f*)sgb); }
        if (tid == 3) { v2f tl = { ssh[4349], ssh[4350] };    __builtin_nontemporal_store(tl, (v2f*)(sgb + 4094)); }
    } else {
        for (int k = tid; k < nb * 10; k += 256)
            __builtin_nontemporal_store(semb[k], egb + k);
        for (int k = tid; k < nb * 16; k += 256)
            __builtin_nontemporal_store(ssh[k + (k >> 4)], sgb + k);
    }
}

extern "C" void kernel_launch(void* const* d_in, const int* in_sizes, int n_in,
                              void* d_out, int out_size, void* d_ws, size_t ws_size,
                              hipStream_t stream) {
    const float* pos  = (const float*)d_in[0];
    const float* qpos = (const float*)d_in[1];
    const float* feat = (const float*)d_in[2];
    const int*   esrc = (const int*)d_in[3];
    const int*   edst = (const int*)d_in[4];
    float* out = (float*)d_out;

    const int Ftot = in_sizes[2];   // 320000
    const int E    = in_sizes[3];   // 3000000

    const unsigned long long OFF_FEAT = 2;
    const unsigned long long OFF_SRC  = OFF_FEAT + (unsigned long long)Ftot;
    const unsigned long long OFF_DST  = OFF_SRC + (unsigned long long)E;
    const unsigned long long OFF_EMB  = OFF_DST + (unsigned long long)E;
    const unsigned long long OFF_SH   = OFF_EMB + 10ULL * E;
    const unsigned long long OFF_LEN  = OFF_SH  + 16ULL * E;

    const int n2feat    = Ftot / 2;
    const int nblk_edge = (E + 255) / 256;
    const int nblk_feat = (n2feat + 255) / 256;

    fused_kernel<<<nblk_edge + nblk_feat, 256, 0, stream>>>(
        pos, qpos, feat, esrc, edst, out,
        E, nblk_edge, n2feat, OFF_SRC, OFF_DST, OFF_EMB, OFF_SH, OFF_LEN);
}